// Round 5
// baseline (4008.875 us; speedup 1.0000x reference)
//
#include <hip/hip_runtime.h>
#include <cmath>

namespace {

constexpr int Dm  = 512;
constexpr int Bn  = 32;
constexpr int Lq  = 16;
constexpr int V1  = 8193;
constexpr int DFF = 2048;
constexpr int NL  = 2;

constexpr int NB    = 128;   // persistent blocks (all co-resident, <=1/CU)
constexpr int NT    = 256;   // threads per block
constexpr int SHARD = 8;
constexpr int SHSZ  = NB / SHARD;  // 16 arrivals per shard

struct Params {
  const int*   meanings;
  const float* emb;
  const float* v2e;
  const float* e2v_w; const float* e2v_b;
  const float* sa_qkv_w; const float* sa_qkv_b;
  const float* sa_out_w; const float* sa_out_b;
  const float* ca_qkv_w; const float* ca_qkv_b;
  const float* ca_out_w; const float* ca_out_b;
  const float* ffn_w1; const float* ffn_b1;
  const float* ffn_w2; const float* ffn_b2;
  const float* ln1_g; const float* ln1_b;
  const float* ln2_g; const float* ln2_b;
  const float* ln3_g; const float* ln3_b;
  unsigned* bar;
  float* src; float* x; float* aout; float* caCp;
  float* qkvp; float* sop; float* h1p; float* f2p; float* lp;
  float* kcache; float* vcache;
  float* outToks; float* outLogits;
};

// ---- coherent (LLC-level, sc1) scalar/pair accessors for activations ----
// Relaxed agent-scope atomics bypass the per-XCD L2 -> no barrier flushes
// needed; weights stay plain (L2-cached, never invalidated).
__device__ __forceinline__ float g_ld(const float* p) {
  return __hip_atomic_load(p, __ATOMIC_RELAXED, __HIP_MEMORY_SCOPE_AGENT);
}
__device__ __forceinline__ void g_st(float* p, float v) {
  __hip_atomic_store(p, v, __ATOMIC_RELAXED, __HIP_MEMORY_SCOPE_AGENT);
}
__device__ __forceinline__ float2 g_ld2(const float* p) {
  unsigned long long u = __hip_atomic_load((const unsigned long long*)p,
      __ATOMIC_RELAXED, __HIP_MEMORY_SCOPE_AGENT);
  float2 r;
  r.x = __uint_as_float((unsigned)u);
  r.y = __uint_as_float((unsigned)(u >> 32));
  return r;
}
__device__ __forceinline__ void g_st2(float* p, float a, float b) {
  unsigned long long u = (unsigned long long)__float_as_uint(a) |
                         ((unsigned long long)__float_as_uint(b) << 32);
  __hip_atomic_store((unsigned long long*)p, u, __ATOMIC_RELAXED,
                     __HIP_MEMORY_SCOPE_AGENT);
}

__device__ __forceinline__ float wred(float v) {
#pragma unroll
  for (int off = 32; off; off >>= 1) v += __shfl_down(v, off, 64);
  return v;
}

__device__ __forceinline__ float dot4(const float4 w, const float4 x, float a) {
  a = fmaf(w.x, x.x, a); a = fmaf(w.y, x.y, a);
  a = fmaf(w.z, x.z, a); a = fmaf(w.w, x.w, a);
  return a;
}

__device__ __forceinline__ float pe_val(int pos, int t) {
  const int j2 = (t >> 1) << 1;
  const float div = expf((float)j2 * (-9.210340371976184f / 512.0f));
  const float ang = (float)pos * div;
  return (t & 1) ? cosf(ang) : sinf(ang);
}

__global__ __launch_bounds__(512) void init_bar(unsigned* bar) {
  // atomic stores so values are LLC-visible to persist's sc1 atomics
  __hip_atomic_store(bar + threadIdx.x, 0u, __ATOMIC_RELAXED,
                     __HIP_MEMORY_SCOPE_AGENT);
}

// Non-flushing grid barrier: sharded monotonic counters + generation.
// RELEASE arrive drains vmcnt + writes back the (tiny) dirty set; NO
// buffer_inv is ever emitted (all cross-block data uses sc1 accessors).
__device__ void gsync(unsigned* bar, unsigned& target) {
  __syncthreads();
  if (threadIdx.x == 0) {
    asm volatile("" ::: "memory");
    const unsigned old = __hip_atomic_fetch_add(
        bar + (((unsigned)blockIdx.x & 7u) << 5), 1u,
        __ATOMIC_RELEASE, __HIP_MEMORY_SCOPE_AGENT);
    if (old == target * SHSZ - 1u) {  // last arrival in shard for this barrier
      const unsigned mold = __hip_atomic_fetch_add(bar + 256, 1u,
          __ATOMIC_RELAXED, __HIP_MEMORY_SCOPE_AGENT);
      if (mold == target * SHARD - 1u) {
        __hip_atomic_fetch_add(bar + 288, 1u, __ATOMIC_RELAXED,
                               __HIP_MEMORY_SCOPE_AGENT);
      }
    }
    while (__hip_atomic_load(bar + 288, __ATOMIC_RELAXED,
                             __HIP_MEMORY_SCOPE_AGENT) < target) {
      __builtin_amdgcn_s_sleep(1);
    }
    asm volatile("" ::: "memory");
  }
  __syncthreads();
  ++target;
}

// ---- k-chunked batch-amortized GEMM phase (port of round-4 fg_part) -----
// njobs = KS*(N/32) block-jobs; kc = bid % KS constant per block (NB%KS==0)
// so the [32][Kc] x-chunk is staged once (sc1 loads, optional SP-partial sum
// + relu), then row-jobs grid-stride. Weights are plain (L2-hot) loads.
template <int KS, int Kc, int SP, bool RELU>
__device__ void ph_fg(float* smem, const float* __restrict__ xsrc, int xstride,
                      int pstride, const float* __restrict__ W, int K,
                      const float* __restrict__ bias,
                      float* __restrict__ part, int N) {
  const int bid = (int)blockIdx.x;
  const int njobs = KS * (N >> 5);
  if (bid >= njobs) return;
  constexpr int QR = Kc / 4;
  const int kc = bid % KS;
  const int k0 = kc * Kc;
  for (int idx = threadIdx.x; idx < 8 * Kc; idx += NT) {
    const int b = idx / QR, q = idx - b * QR;
    const float* s0 = xsrc + (size_t)b * xstride + k0 + (q << 2);
    float2 lo = g_ld2(s0), hi = g_ld2(s0 + 2);
#pragma unroll
    for (int s = 1; s < SP; ++s) {
      const float2 l2 = g_ld2(s0 + (size_t)s * pstride);
      const float2 h2 = g_ld2(s0 + (size_t)s * pstride + 2);
      lo.x += l2.x; lo.y += l2.y; hi.x += h2.x; hi.y += h2.y;
    }
    if (RELU) {
      lo.x = fmaxf(lo.x, 0.f); lo.y = fmaxf(lo.y, 0.f);
      hi.x = fmaxf(hi.x, 0.f); hi.y = fmaxf(hi.y, 0.f);
    }
    float4 v; v.x = lo.x; v.y = lo.y; v.z = hi.x; v.w = hi.y;
    *(float4*)(smem + b * Kc + ((q ^ (b & 7)) << 2)) = v;
  }
  __syncthreads();
  const int lane = (int)threadIdx.x & 63, wave = (int)threadIdx.x >> 6;
  const int bl = lane & 31, nh = lane >> 5, sw = bl & 7;
  const float* xb = smem + bl * Kc;
  for (int jid = bid; jid < njobs; jid += NB) {
    const int rowjob = (jid / KS) * 4 + wave;
    const int n0 = (rowjob << 3) + (nh << 2);
    const float* w = W + (size_t)n0 * K + k0;
    float a0 = 0.f, a1 = 0.f, a2 = 0.f, a3 = 0.f;
#pragma unroll 4
    for (int qq = 0; qq < QR; ++qq) {
      const float4 xv = *(const float4*)(xb + ((qq ^ sw) << 2));
      const float* wq = w + (qq << 2);
      a0 = dot4(*(const float4*)(wq), xv, a0);
      a1 = dot4(*(const float4*)(wq + K), xv, a1);
      a2 = dot4(*(const float4*)(wq + 2 * K), xv, a2);
      a3 = dot4(*(const float4*)(wq + 3 * K), xv, a3);
    }
    if (kc == 0) {
      a0 += bias[n0]; a1 += bias[n0 + 1]; a2 += bias[n0 + 2]; a3 += bias[n0 + 3];
    }
    float* yb = part + (size_t)kc * 32 * N + (size_t)bl * N + n0;
    g_st2(yb, a0, a1); g_st2(yb + 2, a2, a3);
  }
}

// QKV phase: N=1536 K=512 KS=4 Kc=128, routes q/k/v thirds into
// qkvp = [3][4][32][512]. 192 block-jobs.
__device__ void ph_qkv(float* smem, const float* __restrict__ x,
                       const float* __restrict__ W, const float* __restrict__ bias,
                       float* __restrict__ qkvp) {
  constexpr int Kc = 128, QR = 32;
  const int bid = (int)blockIdx.x;
  const int kc = bid & 3, k0 = kc << 7;
  for (int idx = threadIdx.x; idx < 8 * Kc; idx += NT) {
    const int b = idx / QR, q = idx - b * QR;
    const float* s0 = x + (b << 9) + k0 + (q << 2);
    const float2 lo = g_ld2(s0), hi = g_ld2(s0 + 2);
    float4 v; v.x = lo.x; v.y = lo.y; v.z = hi.x; v.w = hi.y;
    *(float4*)(smem + b * Kc + ((q ^ (b & 7)) << 2)) = v;
  }
  __syncthreads();
  const int lane = (int)threadIdx.x & 63, wave = (int)threadIdx.x >> 6;
  const int bl = lane & 31, nh = lane >> 5, sw = bl & 7;
  const float* xb = smem + bl * Kc;
  for (int jid = bid; jid < 192; jid += NB) {
    const int rowjob = (jid >> 2) * 4 + wave;
    const int n0 = (rowjob << 3) + (nh << 2);  // 0..1535
    const float* w = W + (size_t)n0 * Dm + k0;
    float a0 = 0.f, a1 = 0.f, a2 = 0.f, a3 = 0.f;
#pragma unroll 4
    for (int qq = 0; qq < QR; ++qq) {
      const float4 xv = *(const float4*)(xb + ((qq ^ sw) << 2));
      const float* wq = w + (qq << 2);
      a0 = dot4(*(const float4*)(wq), xv, a0);
      a1 = dot4(*(const float4*)(wq + Dm), xv, a1);
      a2 = dot4(*(const float4*)(wq + 2 * Dm), xv, a2);
      a3 = dot4(*(const float4*)(wq + 3 * Dm), xv, a3);
    }
    if (kc == 0) {
      a0 += bias[n0]; a1 += bias[n0 + 1]; a2 += bias[n0 + 2]; a3 += bias[n0 + 3];
    }
    const int seg = n0 >> 9;
    float* yb = qkvp + (size_t)seg * 65536 + (size_t)kc * 16384 + (bl << 9) + (n0 & 511);
    g_st2(yb, a0, a1); g_st2(yb + 2, a2, a3);
  }
}

__device__ void block_ln(float* s, const float* __restrict__ g,
                         const float* __restrict__ bb, float* red) {
  const int tid = (int)threadIdx.x;
  float ls = 0.f, lq = 0.f;
  for (int t = tid; t < Dm; t += NT) { const float v = s[t]; ls += v; lq += v * v; }
  ls = wred(ls); lq = wred(lq);
  const int wave = tid >> 6, lane = tid & 63;
  if (lane == 0) { red[wave] = ls; red[4 + wave] = lq; }
  __syncthreads();
  const float sum = red[0] + red[1] + red[2] + red[3];
  const float sq  = red[4] + red[5] + red[6] + red[7];
  const float mean = sum * (1.f / Dm);
  const float var  = sq * (1.f / Dm) - mean * mean;
  const float inv  = 1.f / sqrtf(var + 1e-5f);
  __syncthreads();
  for (int t = tid; t < Dm; t += NT) s[t] = (s[t] - mean) * inv * g[t] + bb[t];
}

// per-b attention (blocks 0..31): reduce qkv partials, finalize cache slot
// (plain: block-private), scores + softmax + PV.
__device__ void ph_attn(float* smem, const float* __restrict__ qkvp,
                        float* __restrict__ kcl, float* __restrict__ vcl,
                        float* __restrict__ aout, int pos) {
  const int b = (int)blockIdx.x, tid = (int)threadIdx.x;
  const int lane = tid & 63, wave = tid >> 6;
  float* sQ = smem; float* sK = smem + 512; float* sV = smem + 1024;
  float* sS = smem + 1536;
  const float* qp = qkvp;
  const float* kp = qkvp + 65536;
  const float* vp = qkvp + 131072;
  for (int t = tid; t < Dm; t += NT) {
    const int o = (b << 9) + t;
    const float qv = g_ld(qp + o) + g_ld(qp + o + 16384) + g_ld(qp + o + 32768) + g_ld(qp + o + 49152);
    const float kv = g_ld(kp + o) + g_ld(kp + o + 16384) + g_ld(kp + o + 32768) + g_ld(kp + o + 49152);
    const float vv = g_ld(vp + o) + g_ld(vp + o + 16384) + g_ld(vp + o + 32768) + g_ld(vp + o + 49152);
    sQ[t] = qv; sK[t] = kv; sV[t] = vv;
    const int co = ((pos * Bn + b) << 9) + t;
    kcl[co] = kv; vcl[co] = vv;  // block-private cache: plain stores
  }
  __syncthreads();
  for (int j = wave; j <= pos; j += 4) {
    float acc;
    if (j == pos) {
      acc = dot4(*(const float4*)(sK + (lane << 2)),
                 *(const float4*)(sQ + (lane << 2)), 0.f);
      acc = dot4(*(const float4*)(sK + 256 + (lane << 2)),
                 *(const float4*)(sQ + 256 + (lane << 2)), acc);
    } else {
      const float* kr = kcl + ((size_t)(j * Bn + b) << 9);
      acc = dot4(*(const float4*)(kr + (lane << 2)),
                 *(const float4*)(sQ + (lane << 2)), 0.f);
      acc = dot4(*(const float4*)(kr + 256 + (lane << 2)),
                 *(const float4*)(sQ + 256 + (lane << 2)), acc);
    }
    acc = wred(acc);
    if (lane == 0) sS[j] = acc * 0.044194173824159216f;  // 1/sqrt(512)
  }
  __syncthreads();
  if (tid == 0) {
    float m = -1e30f;
    for (int j = 0; j <= pos; ++j) m = fmaxf(m, sS[j]);
    float s = 0.f;
    for (int j = 0; j <= pos; ++j) { const float e = expf(sS[j] - m); sS[j] = e; s += e; }
    const float inv = 1.f / s;
    for (int j = 0; j <= pos; ++j) sS[j] *= inv;
  }
  __syncthreads();
  for (int t = tid; t < Dm; t += NT) {
    float acc = sS[pos] * sV[t];
    for (int j = 0; j < pos; ++j) acc += sS[j] * vcl[((size_t)(j * Bn + b) << 9) + t];
    g_st(aout + (b << 9) + t, acc);
  }
}

__device__ void ph_ln12(float* smem, const float* __restrict__ sop,
                        const float* __restrict__ caCp,
                        const float* __restrict__ g1, const float* __restrict__ b1,
                        const float* __restrict__ g2, const float* __restrict__ b2,
                        float* __restrict__ x) {
  const int b = (int)blockIdx.x, tid = (int)threadIdx.x;
  float* sR = smem; float* red = smem + 512;
  for (int t = tid; t < Dm; t += NT) {
    const int o = (b << 9) + t;
    sR[t] = g_ld(x + o) + g_ld(sop + o) + g_ld(sop + o + 16384) +
            g_ld(sop + o + 32768) + g_ld(sop + o + 49152);
  }
  __syncthreads();
  block_ln(sR, g1, b1, red);
  __syncthreads();
  for (int t = tid; t < Dm; t += NT) {
    const int o = (b << 9) + t;
    sR[t] += g_ld(caCp + o) + g_ld(caCp + o + 16384) +
             g_ld(caCp + o + 32768) + g_ld(caCp + o + 49152);
  }
  __syncthreads();
  block_ln(sR, g2, b2, red);
  __syncthreads();
  for (int t = tid; t < Dm; t += NT) g_st(x + (b << 9) + t, sR[t]);
}

__device__ void ph_ln3(float* smem, const float* __restrict__ f2p,
                       const float* __restrict__ g3, const float* __restrict__ bb3,
                       float* __restrict__ x) {
  const int b = (int)blockIdx.x, tid = (int)threadIdx.x;
  float* sR = smem; float* red = smem + 512;
  for (int t = tid; t < Dm; t += NT) {
    const int o = (b << 9) + t;
    float v = g_ld(x + o);
#pragma unroll
    for (int kc = 0; kc < 8; ++kc) v += g_ld(f2p + kc * 16384 + o);
    sR[t] = v;
  }
  __syncthreads();
  block_ln(sR, g3, bb3, red);
  __syncthreads();
  for (int t = tid; t < Dm; t += NT) g_st(x + (b << 9) + t, sR[t]);
}

__device__ void ph_src(const int* __restrict__ meanings,
                       const float* __restrict__ emb, float* __restrict__ src) {
  const int b = (int)blockIdx.x;
  int m[8];
#pragma unroll
  for (int ty = 0; ty < 8; ++ty) m[ty] = meanings[b * 8 + ty] + ty * 32;
  for (int t = (int)threadIdx.x; t < Dm; t += NT) {
    float s = 0.f;
#pragma unroll
    for (int ty = 0; ty < 8; ++ty) s += emb[(size_t)m[ty] * Dm + t];
    g_st(src + b * Dm + t, s);
  }
}

__device__ void ph_embed0(const float* __restrict__ v2e, float* __restrict__ x, int b) {
  for (int t = (int)threadIdx.x; t < Dm; t += NT)
    g_st(x + (b << 9) + t, v2e[(size_t)(V1 - 1) * Dm + t] + pe_val(0, t));
}

// per-b: logit row 8192, reduce 2 logits parts -> final rows, argmax,
// next-token embed
__device__ void ph_argmax(float* smem, float* __restrict__ x,
                          const float* __restrict__ e2v_w, const float* __restrict__ e2v_b,
                          const float* __restrict__ v2e, const float* __restrict__ lp,
                          float* __restrict__ outLogits, float* __restrict__ outToks,
                          int i) {
  const int b = (int)blockIdx.x, tid = (int)threadIdx.x;
  const int lane = tid & 63, wave = tid >> 6;
  float* red = smem;
  float* sv  = smem + 8;
  int*   si  = (int*)(smem + 8 + NT);
  float ls = 0.f;
  for (int t = tid; t < Dm; t += NT)
    ls += g_ld(x + (b << 9) + t) * e2v_w[(size_t)8192 * Dm + t];
  ls = wred(ls);
  if (lane == 0) red[wave] = ls;
  __syncthreads();
  float* row = outLogits + ((size_t)i * Bn + b) * V1;
  if (tid == 0) {
    const float lg = red[0] + red[1] + red[2] + red[3] + e2v_b[8192];
    g_st(row + 8192, lg);
    red[4] = lg;
  }
  __syncthreads();
  const float lg = red[4];
  float best = -1e30f; int bi = 0;
  for (int v0 = tid * 2; v0 < 8192; v0 += NT * 2) {
    const float2 a = g_ld2(lp + (b << 13) + v0);
    const float2 c = g_ld2(lp + 262144 + (b << 13) + v0);
    const float va = a.x + c.x, vb = a.y + c.y;
    g_st(row + v0, va); g_st(row + v0 + 1, vb);
    if (va > best) { best = va; bi = v0; }      // ascending per-thread keeps
    if (vb > best) { best = vb; bi = v0 + 1; }  // first max on ties
  }
  sv[tid] = best; si[tid] = bi;
  __syncthreads();
  for (int off = 128; off; off >>= 1) {
    if (tid < off) {
      const float v2 = sv[tid + off]; const int i2 = si[tid + off];
      if (v2 > sv[tid] || (v2 == sv[tid] && i2 < si[tid])) { sv[tid] = v2; si[tid] = i2; }
    }
    __syncthreads();
  }
  if (tid == 0) {
    int tok = si[0];
    if (lg > sv[0]) tok = 8192;  // last index wins only on strictly greater
    g_st(outToks + i * Bn + b, (float)tok);
    si[0] = tok;
  }
  __syncthreads();
  const int tok = si[0];
  if (i + 1 < Lq) {
    for (int t = tid; t < Dm; t += NT)
      g_st(x + (b << 9) + t, v2e[(size_t)tok * Dm + t] + pe_val(i + 1, t));
  }
}

__global__ __launch_bounds__(NT) void persist(Params p) {
  __shared__ float smem[8192];  // 32 KB, unioned across phases
  const int bid = (int)blockIdx.x;
  unsigned target = 1;

  // setup: src sums
  if (bid < Bn) ph_src(p.meanings, p.emb, p.src);
  gsync(p.bar, target);

  // cross-attn constants (memory len 1): caCp[l] = parts of Wo@(Wv src+bv)+bo
  for (int l = 0; l < NL; ++l) {
    ph_fg<4, 128, 1, false>(smem, p.src, Dm, 0,
        p.ca_qkv_w + ((size_t)l * 3 + 2) * Dm * Dm, Dm,
        p.ca_qkv_b + l * 3 * Dm + 2 * Dm, p.sop, Dm);
    gsync(p.bar, target);
    ph_fg<4, 128, 4, false>(smem, p.sop, Dm, 16384,
        p.ca_out_w + (size_t)l * Dm * Dm, Dm,
        p.ca_out_b + l * Dm, p.caCp + (size_t)l * 65536, Dm);
    if (l == 0 && bid >= 64 && bid < 96) ph_embed0(p.v2e, p.x, bid - 64);
    gsync(p.bar, target);
  }

  for (int i = 0; i < Lq; ++i) {
    for (int l = 0; l < NL; ++l) {
      float* kcl = p.kcache + (size_t)l * Lq * Bn * Dm;
      float* vcl = p.vcache + (size_t)l * Lq * Bn * Dm;
      ph_qkv(smem, p.x, p.sa_qkv_w + (size_t)l * 3 * Dm * Dm,
             p.sa_qkv_b + l * 3 * Dm, p.qkvp);
      gsync(p.bar, target);
      if (bid < Bn) ph_attn(smem, p.qkvp, kcl, vcl, p.aout, i);
      gsync(p.bar, target);
      ph_fg<4, 128, 1, false>(smem, p.aout, Dm, 0,
          p.sa_out_w + (size_t)l * Dm * Dm, Dm, p.sa_out_b + l * Dm, p.sop, Dm);
      gsync(p.bar, target);
      if (bid < Bn) ph_ln12(smem, p.sop, p.caCp + (size_t)l * 65536,
          p.ln1_g + l * Dm, p.ln1_b + l * Dm, p.ln2_g + l * Dm, p.ln2_b + l * Dm, p.x);
      gsync(p.bar, target);
      ph_fg<4, 128, 1, false>(smem, p.x, Dm, 0,
          p.ffn_w1 + (size_t)l * DFF * Dm, Dm, p.ffn_b1 + l * DFF, p.h1p, DFF);
      gsync(p.bar, target);
      ph_fg<8, 256, 4, true>(smem, p.h1p, DFF, 65536,
          p.ffn_w2 + (size_t)l * Dm * DFF, DFF, p.ffn_b2 + l * Dm, p.f2p, Dm);
      gsync(p.bar, target);
      if (bid < Bn) ph_ln3(smem, p.f2p, p.ln3_g + l * Dm, p.ln3_b + l * Dm, p.x);
      gsync(p.bar, target);
    }
    ph_fg<2, 256, 1, false>(smem, p.x, Dm, 0, p.e2v_w, Dm, p.e2v_b, p.lp, 8192);
    gsync(p.bar, target);
    if (bid < Bn) ph_argmax(smem, p.x, p.e2v_w, p.e2v_b, p.v2e, p.lp,
                            p.outLogits, p.outToks, i);
    gsync(p.bar, target);
  }
}

}  // namespace

extern "C" void kernel_launch(void* const* d_in, const int* in_sizes, int n_in,
                              void* d_out, int out_size, void* d_ws, size_t ws_size,
                              hipStream_t stream) {
  (void)in_sizes; (void)n_in; (void)out_size; (void)ws_size;
  char* ws = (char*)d_ws;

  Params p;
  p.meanings = (const int*)d_in[0];
  p.emb      = (const float*)d_in[1];
  p.v2e      = (const float*)d_in[2];
  p.e2v_w    = (const float*)d_in[3];
  p.e2v_b    = (const float*)d_in[4];
  p.sa_qkv_w = (const float*)d_in[5];
  p.sa_qkv_b = (const float*)d_in[6];
  p.sa_out_w = (const float*)d_in[7];
  p.sa_out_b = (const float*)d_in[8];
  p.ca_qkv_w = (const float*)d_in[9];
  p.ca_qkv_b = (const float*)d_in[10];
  p.ca_out_w = (const float*)d_in[11];
  p.ca_out_b = (const float*)d_in[12];
  p.ffn_w1   = (const float*)d_in[13];
  p.ffn_b1   = (const float*)d_in[14];
  p.ffn_w2   = (const float*)d_in[15];
  p.ffn_b2   = (const float*)d_in[16];
  p.ln1_g = (const float*)d_in[17]; p.ln1_b = (const float*)d_in[18];
  p.ln2_g = (const float*)d_in[19]; p.ln2_b = (const float*)d_in[20];
  p.ln3_g = (const float*)d_in[21]; p.ln3_b = (const float*)d_in[22];

  p.bar = (unsigned*)ws;
  float* f = (float*)(ws + 4096);
  p.src  = f;  f += 16384;               // [32][512]
  p.x    = f;  f += 16384;               // [32][512]
  p.aout = f;  f += 16384;               // [32][512]
  p.caCp = f;  f += 131072;              // [NL][4][32][512]
  float* regA = f;  f += 655360;         // per-step partials (union)
  p.kcache = f; f += 524288;             // [NL][16][32][512]
  p.vcache = f;
  p.qkvp = regA;                         // [3][4][32][512] = 196608
  p.sop  = regA + 196608;                // [4][32][512]    = 65536
  p.h1p  = regA + 262144;                // [4][32][2048]   = 262144
  p.f2p  = regA + 524288;                // [8][32][512]    = 131072
  p.lp   = regA;                         // [2][32][8192]   = 524288 (aliases dead bufs)

  p.outToks   = (float*)d_out;
  p.outLogits = (float*)d_out + Lq * Bn;

  init_bar<<<1, 512, 0, stream>>>(p.bar);
  persist<<<NB, NT, 0, stream>>>(p);
}

// Round 6
// 3237.165 us; speedup vs baseline: 1.2384x; 1.2384x over previous
//
#include <hip/hip_runtime.h>
#include <cmath>

namespace {

constexpr int Dm  = 512;
constexpr int Bn  = 32;
constexpr int Lq  = 16;
constexpr int V1  = 8193;
constexpr int DFF = 2048;
constexpr int NL  = 2;
constexpr int NT  = 256;

// ---- coherent (LLC-level, sc1) accessors for cross-block activations ----
__device__ __forceinline__ float g_ld(const float* p) {
  return __hip_atomic_load(p, __ATOMIC_RELAXED, __HIP_MEMORY_SCOPE_AGENT);
}
__device__ __forceinline__ void g_st(float* p, float v) {
  __hip_atomic_store(p, v, __ATOMIC_RELAXED, __HIP_MEMORY_SCOPE_AGENT);
}
__device__ __forceinline__ float2 g_ld2(const float* p) {
  unsigned long long u = __hip_atomic_load((const unsigned long long*)p,
      __ATOMIC_RELAXED, __HIP_MEMORY_SCOPE_AGENT);
  float2 r;
  r.x = __uint_as_float((unsigned)u);
  r.y = __uint_as_float((unsigned)(u >> 32));
  return r;
}
__device__ __forceinline__ void g_st2(float* p, float a, float b) {
  unsigned long long u = (unsigned long long)__float_as_uint(a) |
                         ((unsigned long long)__float_as_uint(b) << 32);
  __hip_atomic_store((unsigned long long*)p, u, __ATOMIC_RELAXED,
                     __HIP_MEMORY_SCOPE_AGENT);
}

__device__ __forceinline__ float wred(float v) {
#pragma unroll
  for (int off = 32; off; off >>= 1) v += __shfl_down(v, off, 64);
  return v;
}

__device__ __forceinline__ float dot4(const float4 w, const float4 x, float a) {
  a = fmaf(w.x, x.x, a); a = fmaf(w.y, x.y, a);
  a = fmaf(w.z, x.z, a); a = fmaf(w.w, x.w, a);
  return a;
}

__device__ __forceinline__ float pe_val(int pos, int t) {
  const int j2 = (t >> 1) << 1;
  const float div = expf((float)j2 * (-9.210340371976184f / 512.0f));
  const float ang = (float)pos * div;
  return (t & 1) ? cosf(ang) : sinf(ang);
}

// ticket/wait primitives (verified machinery: round-5 gsync variant)
__device__ __forceinline__ void wait_ctr(const unsigned* c, unsigned n) {
  if (threadIdx.x == 0) {
    while (__hip_atomic_load(c, __ATOMIC_RELAXED, __HIP_MEMORY_SCOPE_AGENT) < n)
      __builtin_amdgcn_s_sleep(2);
    asm volatile("" ::: "memory");
  }
  __syncthreads();
}

__device__ void block_ln(float* s, const float* __restrict__ g,
                         const float* __restrict__ bb, float* red) {
  const int tid = (int)threadIdx.x;
  float ls = 0.f, lq = 0.f;
  for (int t = tid; t < Dm; t += NT) { const float v = s[t]; ls += v; lq += v * v; }
  ls = wred(ls); lq = wred(lq);
  const int wave = tid >> 6, lane = tid & 63;
  if (lane == 0) { red[wave] = ls; red[4 + wave] = lq; }
  __syncthreads();
  const float sum = red[0] + red[1] + red[2] + red[3];
  const float sq  = red[4] + red[5] + red[6] + red[7];
  const float mean = sum * (1.f / Dm);
  const float var  = sq * (1.f / Dm) - mean * mean;
  const float inv  = 1.f / sqrtf(var + 1e-5f);
  __syncthreads();
  for (int t = tid; t < Dm; t += NT) s[t] = (s[t] - mean) * inv * g[t] + bb[t];
}

__global__ __launch_bounds__(512) void init_bar(unsigned* bar) {
  const int i = (int)blockIdx.x * 512 + (int)threadIdx.x;
  __hip_atomic_store(bar + i, 0u, __ATOMIC_RELAXED, __HIP_MEMORY_SCOPE_AGENT);
}

__global__ __launch_bounds__(512) void src_kernel(const int* __restrict__ meanings,
    const float* __restrict__ emb, float* __restrict__ src) {
  const int b = (int)blockIdx.x, t = (int)threadIdx.x;
  float s = 0.f;
#pragma unroll
  for (int ty = 0; ty < 8; ++ty) {
    const int idx = meanings[b * 8 + ty] + ty * 32;
    s += emb[(size_t)idx * Dm + t];
  }
  g_st(src + b * Dm + t, s);
}

__global__ __launch_bounds__(512) void embed0(const float* __restrict__ v2e,
                                              float* __restrict__ x) {
  const int b = (int)blockIdx.x, t = (int)threadIdx.x;
  g_st(x + (b << 9) + t, v2e[(size_t)(V1 - 1) * Dm + t] + pe_val(0, t));
}

// ---- generic partial GEMM (setup only; round-4 fg_part with sc1 I/O) ----
template <int KS, int Kc, int SP, bool RELU>
__global__ __launch_bounds__(NT) void k_fg(const float* __restrict__ xsrc, int xstride,
    int pstride, const float* __restrict__ W, int K, const float* __restrict__ bias,
    float* __restrict__ part, int N) {
  constexpr int QR = Kc / 4;
  __shared__ float smem[32 * Kc];
  const int bid = (int)blockIdx.x, tid = (int)threadIdx.x;
  const int kc = bid % KS, k0 = kc * Kc;
  for (int idx = tid; idx < 8 * Kc; idx += NT) {
    const int b = idx / QR, q = idx - b * QR;
    const float* s0 = xsrc + (size_t)b * xstride + k0 + (q << 2);
    float2 lo = g_ld2(s0), hi = g_ld2(s0 + 2);
#pragma unroll
    for (int s = 1; s < SP; ++s) {
      const float2 l2 = g_ld2(s0 + (size_t)s * pstride);
      const float2 h2 = g_ld2(s0 + (size_t)s * pstride + 2);
      lo.x += l2.x; lo.y += l2.y; hi.x += h2.x; hi.y += h2.y;
    }
    if (RELU) {
      lo.x = fmaxf(lo.x, 0.f); lo.y = fmaxf(lo.y, 0.f);
      hi.x = fmaxf(hi.x, 0.f); hi.y = fmaxf(hi.y, 0.f);
    }
    float4 v; v.x = lo.x; v.y = lo.y; v.z = hi.x; v.w = hi.y;
    *(float4*)(smem + b * Kc + ((q ^ (b & 7)) << 2)) = v;
  }
  __syncthreads();
  const int lane = tid & 63, wave = tid >> 6;
  const int bl = lane & 31, nh = lane >> 5, sw = bl & 7;
  const float* xb = smem + bl * Kc;
  const int rowjob = (bid / KS) * 4 + wave;
  const int n0 = (rowjob << 3) + (nh << 2);
  const float* w = W + (size_t)n0 * K + k0;
  float a0 = 0.f, a1 = 0.f, a2 = 0.f, a3 = 0.f;
#pragma unroll 4
  for (int qq = 0; qq < QR; ++qq) {
    const float4 xv = *(const float4*)(xb + ((qq ^ sw) << 2));
    const float* wq = w + (qq << 2);
    a0 = dot4(*(const float4*)(wq), xv, a0);
    a1 = dot4(*(const float4*)(wq + K), xv, a1);
    a2 = dot4(*(const float4*)(wq + 2 * K), xv, a2);
    a3 = dot4(*(const float4*)(wq + 3 * K), xv, a3);
  }
  if (kc == 0) {
    a0 += bias[n0]; a1 += bias[n0 + 1]; a2 += bias[n0 + 2]; a3 += bias[n0 + 3];
  }
  float* yb = part + (size_t)kc * 32 * N + (size_t)bl * N + n0;
  g_st2(yb, a0, a1); g_st2(yb + 2, a2, a3);
}

// ---- A: qkv partials (192 jobs) + last-32 tails do per-b attention ------
__global__ __launch_bounds__(NT) void k_qkv_attn(const float* __restrict__ x,
    const float* __restrict__ W, const float* __restrict__ bias,
    float* __restrict__ qkvp, float* __restrict__ kcl, float* __restrict__ vcl,
    float* __restrict__ aout, unsigned* ctr, int pos) {
  __shared__ float smem[4096];
  __shared__ int tkt_s;
  const int bid = (int)blockIdx.x, tid = (int)threadIdx.x;
  const int lane = tid & 63, wave = tid >> 6;
  {
    constexpr int Kc = 128;
    const int kc = bid & 3, k0 = kc << 7;
    for (int idx = tid; idx < 1024; idx += NT) {
      const int b = idx >> 5, q = idx & 31;
      const float* s0 = x + (b << 9) + k0 + (q << 2);
      const float2 lo = g_ld2(s0), hi = g_ld2(s0 + 2);
      float4 v; v.x = lo.x; v.y = lo.y; v.z = hi.x; v.w = hi.y;
      *(float4*)(smem + b * Kc + ((q ^ (b & 7)) << 2)) = v;
    }
    __syncthreads();
    const int bl = lane & 31, nh = lane >> 5, sw = bl & 7;
    const float* xb = smem + bl * Kc;
    const int rowjob = (bid >> 2) * 4 + wave;
    const int n0 = (rowjob << 3) + (nh << 2);  // 0..1535
    const float* w = W + (size_t)n0 * Dm + k0;
    float a0 = 0.f, a1 = 0.f, a2 = 0.f, a3 = 0.f;
#pragma unroll 4
    for (int qq = 0; qq < 32; ++qq) {
      const float4 xv = *(const float4*)(xb + ((qq ^ sw) << 2));
      const float* wq = w + (qq << 2);
      a0 = dot4(*(const float4*)(wq), xv, a0);
      a1 = dot4(*(const float4*)(wq + Dm), xv, a1);
      a2 = dot4(*(const float4*)(wq + 2 * Dm), xv, a2);
      a3 = dot4(*(const float4*)(wq + 3 * Dm), xv, a3);
    }
    if (kc == 0) {
      a0 += bias[n0]; a1 += bias[n0 + 1]; a2 += bias[n0 + 2]; a3 += bias[n0 + 3];
    }
    const int seg = n0 >> 9;
    float* yb = qkvp + (size_t)seg * 65536 + (size_t)kc * 16384 + (bl << 9) + (n0 & 511);
    g_st2(yb, a0, a1); g_st2(yb + 2, a2, a3);
  }
  __syncthreads();
  if (tid == 0)
    tkt_s = (int)__hip_atomic_fetch_add(ctr, 1u, __ATOMIC_RELEASE, __HIP_MEMORY_SCOPE_AGENT);
  __syncthreads();
  const int tkt = tkt_s;
  if (tkt < 160) return;
  const int b = tkt - 160;
  wait_ctr(ctr, 192);
  // per-b attention (verified round-5 body)
  float* sQ = smem; float* sK = smem + 512; float* sV = smem + 1024;
  float* sS = smem + 1536;
  const float* qp = qkvp;
  const float* kp = qkvp + 65536;
  const float* vp = qkvp + 131072;
  for (int t = tid; t < Dm; t += NT) {
    const int o = (b << 9) + t;
    const float qv = g_ld(qp + o) + g_ld(qp + o + 16384) + g_ld(qp + o + 32768) + g_ld(qp + o + 49152);
    const float kv = g_ld(kp + o) + g_ld(kp + o + 16384) + g_ld(kp + o + 32768) + g_ld(kp + o + 49152);
    const float vv = g_ld(vp + o) + g_ld(vp + o + 16384) + g_ld(vp + o + 32768) + g_ld(vp + o + 49152);
    sQ[t] = qv; sK[t] = kv; sV[t] = vv;
    const int co = ((pos * Bn + b) << 9) + t;
    kcl[co] = kv; vcl[co] = vv;  // cross-kernel only: plain ok
  }
  __syncthreads();
  for (int j = wave; j <= pos; j += 4) {
    float acc;
    if (j == pos) {
      acc = dot4(*(const float4*)(sK + (lane << 2)),
                 *(const float4*)(sQ + (lane << 2)), 0.f);
      acc = dot4(*(const float4*)(sK + 256 + (lane << 2)),
                 *(const float4*)(sQ + 256 + (lane << 2)), acc);
    } else {
      const float* kr = kcl + ((size_t)(j * Bn + b) << 9);
      acc = dot4(*(const float4*)(kr + (lane << 2)),
                 *(const float4*)(sQ + (lane << 2)), 0.f);
      acc = dot4(*(const float4*)(kr + 256 + (lane << 2)),
                 *(const float4*)(sQ + 256 + (lane << 2)), acc);
    }
    acc = wred(acc);
    if (lane == 0) sS[j] = acc * 0.044194173824159216f;  // 1/sqrt(512)
  }
  __syncthreads();
  if (tid == 0) {
    float m = -1e30f;
    for (int j = 0; j <= pos; ++j) m = fmaxf(m, sS[j]);
    float s = 0.f;
    for (int j = 0; j <= pos; ++j) { const float e = expf(sS[j] - m); sS[j] = e; s += e; }
    const float inv = 1.f / s;
    for (int j = 0; j <= pos; ++j) sS[j] *= inv;
  }
  __syncthreads();
  for (int t = tid; t < Dm; t += NT) {
    float acc = sS[pos] * sV[t];
    for (int j = 0; j < pos; ++j) acc += sS[j] * vcl[((size_t)(j * Bn + b) << 9) + t];
    g_st(aout + (b << 9) + t, acc);
  }
}

// ---- B: saout parts -> ln12 tails -> ffn1 parts -> ffn2 parts -> ln3 ----
__global__ __launch_bounds__(NT) void k_post(
    const float* __restrict__ aout, const float* __restrict__ caCp_l,
    float* __restrict__ x,
    const float* __restrict__ saW, const float* __restrict__ saB,
    const float* __restrict__ g1, const float* __restrict__ b1,
    const float* __restrict__ g2, const float* __restrict__ b2,
    const float* __restrict__ f1W, const float* __restrict__ f1b,
    const float* __restrict__ f2W, const float* __restrict__ f2b,
    const float* __restrict__ g3, const float* __restrict__ b3,
    float* __restrict__ sop, float* __restrict__ h1p, float* __restrict__ f2p,
    unsigned* ctr) {
  __shared__ float smem[8192];
  __shared__ float red_s[8];
  __shared__ int tkt_s;
  const int bid = (int)blockIdx.x, tid = (int)threadIdx.x;
  const int lane = tid & 63, wave = tid >> 6;
  const int bl = lane & 31, nh = lane >> 5, sw = bl & 7;
  unsigned* c0 = ctr; unsigned* c1 = ctr + 32; unsigned* c2 = ctr + 64;
  unsigned* c3 = ctr + 96;

  if (bid < 64) {  // S: saout partial job
    const int kc = bid & 3, k0 = kc << 7;
    for (int idx = tid; idx < 1024; idx += NT) {
      const int b = idx >> 5, q = idx & 31;
      const float* s0 = aout + (b << 9) + k0 + (q << 2);
      const float2 lo = g_ld2(s0), hi = g_ld2(s0 + 2);
      float4 v; v.x = lo.x; v.y = lo.y; v.z = hi.x; v.w = hi.y;
      *(float4*)(smem + (b << 7) + ((q ^ (b & 7)) << 2)) = v;
    }
    __syncthreads();
    const float* xb = smem + (bl << 7);
    const int rowjob = (bid >> 2) * 4 + wave;
    const int n0 = (rowjob << 3) + (nh << 2);  // <512
    const float* w = saW + (size_t)n0 * Dm + k0;
    float a0 = 0.f, a1 = 0.f, a2 = 0.f, a3 = 0.f;
#pragma unroll 4
    for (int qq = 0; qq < 32; ++qq) {
      const float4 xv = *(const float4*)(xb + ((qq ^ sw) << 2));
      const float* wq = w + (qq << 2);
      a0 = dot4(*(const float4*)(wq), xv, a0);
      a1 = dot4(*(const float4*)(wq + Dm), xv, a1);
      a2 = dot4(*(const float4*)(wq + 2 * Dm), xv, a2);
      a3 = dot4(*(const float4*)(wq + 3 * Dm), xv, a3);
    }
    if (kc == 0) {
      a0 += saB[n0]; a1 += saB[n0 + 1]; a2 += saB[n0 + 2]; a3 += saB[n0 + 3];
    }
    float* yb = sop + (size_t)kc * 16384 + (bl << 9) + n0;
    g_st2(yb, a0, a1); g_st2(yb + 2, a2, a3);
    __syncthreads();
    if (tid == 0)
      tkt_s = (int)__hip_atomic_fetch_add(c0, 1u, __ATOMIC_RELEASE, __HIP_MEMORY_SCOPE_AGENT);
    __syncthreads();
    const int tkt = tkt_s;
    if (tkt >= 32) {  // ln12 tail for b
      const int b = tkt - 32;
      wait_ctr(c0, 64);
      float* sR = smem;
      for (int t = tid; t < Dm; t += NT) {
        const int o = (b << 9) + t;
        sR[t] = g_ld(x + o) + g_ld(sop + o) + g_ld(sop + o + 16384) +
                g_ld(sop + o + 32768) + g_ld(sop + o + 49152);
      }
      __syncthreads();
      block_ln(sR, g1, b1, red_s);
      __syncthreads();
      for (int t = tid; t < Dm; t += NT) {
        const int o = (b << 9) + t;
        sR[t] += g_ld(caCp_l + o) + g_ld(caCp_l + o + 16384) +
                 g_ld(caCp_l + o + 32768) + g_ld(caCp_l + o + 49152);
      }
      __syncthreads();
      block_ln(sR, g2, b2, red_s);
      __syncthreads();
      for (int t = tid; t < Dm; t += NT) g_st(x + (b << 9) + t, sR[t]);
      __syncthreads();
      if (tid == 0)
        __hip_atomic_fetch_add(c1, 1u, __ATOMIC_RELEASE, __HIP_MEMORY_SCOPE_AGENT);
    }
  }

  wait_ctr(c1, 32);  // x now holds ln12 output

  {  // F1: ffn1 partial job (jid = bid, 256 jobs)
    const int kc = bid & 3, k0 = kc << 7;
    for (int idx = tid; idx < 1024; idx += NT) {
      const int b = idx >> 5, q = idx & 31;
      const float* s0 = x + (b << 9) + k0 + (q << 2);
      const float2 lo = g_ld2(s0), hi = g_ld2(s0 + 2);
      float4 v; v.x = lo.x; v.y = lo.y; v.z = hi.x; v.w = hi.y;
      *(float4*)(smem + (b << 7) + ((q ^ (b & 7)) << 2)) = v;
    }
    __syncthreads();
    const float* xb = smem + (bl << 7);
    const int rowjob = (bid >> 2) * 4 + wave;
    const int n0 = (rowjob << 3) + (nh << 2);  // <2048
    const float* w = f1W + (size_t)n0 * Dm + k0;
    float a0 = 0.f, a1 = 0.f, a2 = 0.f, a3 = 0.f;
#pragma unroll 4
    for (int qq = 0; qq < 32; ++qq) {
      const float4 xv = *(const float4*)(xb + ((qq ^ sw) << 2));
      const float* wq = w + (qq << 2);
      a0 = dot4(*(const float4*)(wq), xv, a0);
      a1 = dot4(*(const float4*)(wq + Dm), xv, a1);
      a2 = dot4(*(const float4*)(wq + 2 * Dm), xv, a2);
      a3 = dot4(*(const float4*)(wq + 3 * Dm), xv, a3);
    }
    if (kc == 0) {
      a0 += f1b[n0]; a1 += f1b[n0 + 1]; a2 += f1b[n0 + 2]; a3 += f1b[n0 + 3];
    }
    float* yb = h1p + (size_t)kc * 65536 + (size_t)bl * DFF + n0;
    g_st2(yb, a0, a1); g_st2(yb + 2, a2, a3);
  }
  __syncthreads();
  if (tid == 0)
    __hip_atomic_fetch_add(c2, 1u, __ATOMIC_RELEASE, __HIP_MEMORY_SCOPE_AGENT);
  if (bid >= 128) return;

  wait_ctr(c2, 256);  // h1p complete

  {  // F2: ffn2 partial job (jid = bid, 128 jobs), Kc=256, SP=4, relu
    const int kc = bid & 7, k0 = kc << 8;
    for (int idx = tid; idx < 2048; idx += NT) {
      const int b = idx >> 6, q = idx & 63;
      const float* s0 = h1p + (size_t)b * DFF + k0 + (q << 2);
      float2 lo = g_ld2(s0), hi = g_ld2(s0 + 2);
#pragma unroll
      for (int s = 1; s < 4; ++s) {
        const float2 l2 = g_ld2(s0 + (size_t)s * 65536);
        const float2 h2 = g_ld2(s0 + (size_t)s * 65536 + 2);
        lo.x += l2.x; lo.y += l2.y; hi.x += h2.x; hi.y += h2.y;
      }
      lo.x = fmaxf(lo.x, 0.f); lo.y = fmaxf(lo.y, 0.f);
      hi.x = fmaxf(hi.x, 0.f); hi.y = fmaxf(hi.y, 0.f);
      float4 v; v.x = lo.x; v.y = lo.y; v.z = hi.x; v.w = hi.y;
      *(float4*)(smem + (b << 8) + ((q ^ (b & 7)) << 2)) = v;
    }
    __syncthreads();
    const float* xb = smem + (bl << 8);
    const int rowjob = (bid >> 3) * 4 + wave;
    const int n0 = (rowjob << 3) + (nh << 2);  // <512
    const float* w = f2W + (size_t)n0 * DFF + k0;
    float a0 = 0.f, a1 = 0.f, a2 = 0.f, a3 = 0.f;
#pragma unroll 4
    for (int qq = 0; qq < 64; ++qq) {
      const float4 xv = *(const float4*)(xb + ((qq ^ sw) << 2));
      const float* wq = w + (qq << 2);
      a0 = dot4(*(const float4*)(wq), xv, a0);
      a1 = dot4(*(const float4*)(wq + DFF), xv, a1);
      a2 = dot4(*(const float4*)(wq + 2 * DFF), xv, a2);
      a3 = dot4(*(const float4*)(wq + 3 * DFF), xv, a3);
    }
    if (kc == 0) {
      a0 += f2b[n0]; a1 += f2b[n0 + 1]; a2 += f2b[n0 + 2]; a3 += f2b[n0 + 3];
    }
    float* yb = f2p + (size_t)kc * 16384 + (bl << 9) + n0;
    g_st2(yb, a0, a1); g_st2(yb + 2, a2, a3);
  }
  __syncthreads();
  if (tid == 0)
    tkt_s = (int)__hip_atomic_fetch_add(c3, 1u, __ATOMIC_RELEASE, __HIP_MEMORY_SCOPE_AGENT);
  __syncthreads();
  const int tkt = tkt_s;
  if (tkt < 96) return;
  const int b = tkt - 96;
  wait_ctr(c3, 128);
  {  // ln3 tail
    float* sR = smem;
    for (int t = tid; t < Dm; t += NT) {
      const int o = (b << 9) + t;
      float v = g_ld(x + o);
#pragma unroll
      for (int kc = 0; kc < 8; ++kc) v += g_ld(f2p + kc * 16384 + o);
      sR[t] = v;
    }
    __syncthreads();
    block_ln(sR, g3, b3, red_s);
    __syncthreads();
    for (int t = tid; t < Dm; t += NT) g_st(x + (b << 9) + t, sR[t]);
  }
}

// ---- C: logits partials (512 jobs) + last-32 tails argmax + embed -------
__global__ __launch_bounds__(NT) void k_logits(float* __restrict__ x,
    const float* __restrict__ e2v_w, const float* __restrict__ e2v_b,
    const float* __restrict__ v2e, float* __restrict__ lp,
    float* __restrict__ outLogits, float* __restrict__ outToks,
    unsigned* ctr, int i) {
  __shared__ float smem[8192];
  __shared__ float red_s[8];
  __shared__ float lg_s;
  __shared__ float sv[NT];
  __shared__ int   si[NT];
  __shared__ int tkt_s;
  const int bid = (int)blockIdx.x, tid = (int)threadIdx.x;
  const int lane = tid & 63, wave = tid >> 6;
  {
    const int kc = bid & 1, k0 = kc << 8;  // Kc=256
    for (int idx = tid; idx < 2048; idx += NT) {
      const int b = idx >> 6, q = idx & 63;
      const float* s0 = x + (b << 9) + k0 + (q << 2);
      const float2 lo = g_ld2(s0), hi = g_ld2(s0 + 2);
      float4 v; v.x = lo.x; v.y = lo.y; v.z = hi.x; v.w = hi.y;
      *(float4*)(smem + (b << 8) + ((q ^ (b & 7)) << 2)) = v;
    }
    __syncthreads();
    const int bl = lane & 31, nh = lane >> 5, sw = bl & 7;
    const float* xb = smem + (bl << 8);
    const int rowjob = (bid >> 1) * 4 + wave;
    const int n0 = (rowjob << 3) + (nh << 2);  // <8192
    const float* w = e2v_w + (size_t)n0 * Dm + k0;
    float a0 = 0.f, a1 = 0.f, a2 = 0.f, a3 = 0.f;
#pragma unroll 4
    for (int qq = 0; qq < 64; ++qq) {
      const float4 xv = *(const float4*)(xb + ((qq ^ sw) << 2));
      const float* wq = w + (qq << 2);
      a0 = dot4(*(const float4*)(wq), xv, a0);
      a1 = dot4(*(const float4*)(wq + Dm), xv, a1);
      a2 = dot4(*(const float4*)(wq + 2 * Dm), xv, a2);
      a3 = dot4(*(const float4*)(wq + 3 * Dm), xv, a3);
    }
    if (kc == 0) {
      a0 += e2v_b[n0]; a1 += e2v_b[n0 + 1]; a2 += e2v_b[n0 + 2]; a3 += e2v_b[n0 + 3];
    }
    float* yb = lp + (size_t)kc * 262144 + (size_t)((lane & 31)) * 8192 + n0;
    g_st2(yb, a0, a1); g_st2(yb + 2, a2, a3);
  }
  __syncthreads();
  if (tid == 0)
    tkt_s = (int)__hip_atomic_fetch_add(ctr, 1u, __ATOMIC_RELEASE, __HIP_MEMORY_SCOPE_AGENT);
  __syncthreads();
  const int tkt = tkt_s;
  if (tkt < 480) return;
  const int b = tkt - 480;
  wait_ctr(ctr, 512);
  // argmax + embed (verified round-5 body, plain row writes)
  float ls = 0.f;
  for (int t = tid; t < Dm; t += NT)
    ls += g_ld(x + (b << 9) + t) * e2v_w[(size_t)8192 * Dm + t];
  ls = wred(ls);
  if (lane == 0) red_s[wave] = ls;
  __syncthreads();
  float* row = outLogits + ((size_t)i * Bn + b) * V1;
  if (tid == 0) {
    const float lg = red_s[0] + red_s[1] + red_s[2] + red_s[3] + e2v_b[8192];
    row[8192] = lg;
    lg_s = lg;
  }
  __syncthreads();
  const float lg = lg_s;
  float best = -1e30f; int bi = 0;
  for (int v0 = tid * 2; v0 < 8192; v0 += NT * 2) {
    const float2 a = g_ld2(lp + (b << 13) + v0);
    const float2 c = g_ld2(lp + 262144 + (b << 13) + v0);
    const float va = a.x + c.x, vb = a.y + c.y;
    row[v0] = va; row[v0 + 1] = vb;
    if (va > best) { best = va; bi = v0; }      // ascending per-thread keeps
    if (vb > best) { best = vb; bi = v0 + 1; }  // first max on ties
  }
  sv[tid] = best; si[tid] = bi;
  __syncthreads();
  for (int off = 128; off; off >>= 1) {
    if (tid < off) {
      const float v2 = sv[tid + off]; const int i2 = si[tid + off];
      if (v2 > sv[tid] || (v2 == sv[tid] && i2 < si[tid])) { sv[tid] = v2; si[tid] = i2; }
    }
    __syncthreads();
  }
  if (tid == 0) {
    int tok = si[0];
    if (lg > sv[0]) tok = 8192;  // last index wins only on strictly greater
    outToks[i * Bn + b] = (float)tok;
    si[0] = tok;
  }
  __syncthreads();
  const int tok = si[0];
  if (i + 1 < Lq) {
    for (int t = tid; t < Dm; t += NT)
      g_st(x + (b << 9) + t, v2e[(size_t)tok * Dm + t] + pe_val(i + 1, t));
  }
}

}  // namespace

extern "C" void kernel_launch(void* const* d_in, const int* in_sizes, int n_in,
                              void* d_out, int out_size, void* d_ws, size_t ws_size,
                              hipStream_t stream) {
  (void)in_sizes; (void)n_in; (void)out_size; (void)ws_size;
  const int*   meanings  = (const int*)d_in[0];
  const float* emb_table = (const float*)d_in[1];
  const float* v2e_w     = (const float*)d_in[2];
  const float* e2v_w     = (const float*)d_in[3];
  const float* e2v_b     = (const float*)d_in[4];
  const float* sa_qkv_w  = (const float*)d_in[5];
  const float* sa_qkv_b  = (const float*)d_in[6];
  const float* sa_out_w  = (const float*)d_in[7];
  const float* sa_out_b  = (const float*)d_in[8];
  const float* ca_qkv_w  = (const float*)d_in[9];
  const float* ca_qkv_b  = (const float*)d_in[10];
  const float* ca_out_w  = (const float*)d_in[11];
  const float* ca_out_b  = (const float*)d_in[12];
  const float* ffn_w1    = (const float*)d_in[13];
  const float* ffn_b1    = (const float*)d_in[14];
  const float* ffn_w2    = (const float*)d_in[15];
  const float* ffn_b2    = (const float*)d_in[16];
  const float* ln1_g     = (const float*)d_in[17];
  const float* ln1_b     = (const float*)d_in[18];
  const float* ln2_g     = (const float*)d_in[19];
  const float* ln2_b     = (const float*)d_in[20];
  const float* ln3_g     = (const float*)d_in[21];
  const float* ln3_b     = (const float*)d_in[22];

  float* out = (float*)d_out;            // toks [16,32] then logits [16,32,8193]
  float* outLogits = out + Lq * Bn;

  char* ws = (char*)d_ws;
  unsigned* bar = (unsigned*)ws;         // 8192 counters (32 KB)
  float* f = (float*)(ws + 32768);
  float* src  = f;  f += 16384;          // [32][512]
  float* x    = f;  f += 16384;          // [32][512]
  float* aout = f;  f += 16384;          // [32][512]
  float* caCp = f;  f += 131072;         // [NL][4][32][512]
  float* regA = f;  f += 655360;         // per-step partials (union)
  float* kcache = f; f += 524288;        // [NL][16][32][512]
  float* vcache = f;
  float* qkvp = regA;                    // [3][4][32][512] = 196608
  float* sop  = regA + 196608;           // [4][32][512]    = 65536
  float* h1p  = regA + 262144;           // [4][32][2048]   = 262144
  float* f2p  = regA + 524288;           // [8][32][512]    = 131072
  float* lp   = regA;                    // [2][32][8192]   = 524288 (aliases dead bufs)

  int cidx = 0;

  init_bar<<<16, 512, 0, stream>>>(bar);
  src_kernel<<<Bn, 512, 0, stream>>>(meanings, emb_table, src);

  // cross-attn constants (memory len 1): caCp[l] parts of Wo@(Wv src+bv)+bo
  for (int l = 0; l < NL; ++l) {
    k_fg<4, 128, 1, false><<<64, NT, 0, stream>>>(src, Dm, 0,
        ca_qkv_w + ((size_t)l * 3 + 2) * Dm * Dm, Dm,
        ca_qkv_b + l * 3 * Dm + 2 * Dm, sop, Dm);
    k_fg<4, 128, 4, false><<<64, NT, 0, stream>>>(sop, Dm, 16384,
        ca_out_w + (size_t)l * Dm * Dm, Dm,
        ca_out_b + l * Dm, caCp + (size_t)l * 65536, Dm);
  }

  embed0<<<Bn, 512, 0, stream>>>(v2e_w, x);

  for (int i = 0; i < Lq; ++i) {
    for (int l = 0; l < NL; ++l) {
      float* kcl = kcache + (size_t)l * Lq * Bn * Dm;
      float* vcl = vcache + (size_t)l * Lq * Bn * Dm;
      k_qkv_attn<<<192, NT, 0, stream>>>(x,
          sa_qkv_w + (size_t)l * 3 * Dm * Dm, sa_qkv_b + l * 3 * Dm,
          qkvp, kcl, vcl, aout, bar + (cidx++) * 32, i);
      k_post<<<256, NT, 0, stream>>>(aout, caCp + (size_t)l * 65536, x,
          sa_out_w + (size_t)l * Dm * Dm, sa_out_b + l * Dm,
          ln1_g + l * Dm, ln1_b + l * Dm, ln2_g + l * Dm, ln2_b + l * Dm,
          ffn_w1 + (size_t)l * DFF * Dm, ffn_b1 + l * DFF,
          ffn_w2 + (size_t)l * Dm * DFF, ffn_b2 + l * Dm,
          ln3_g + l * Dm, ln3_b + l * Dm,
          sop, h1p, f2p, bar + cidx * 32);
      cidx += 4;
    }
    k_logits<<<512, NT, 0, stream>>>(x, e2v_w, e2v_b, v2e_w, lp,
        outLogits, out, bar + (cidx++) * 32, i);
  }
}

// Round 7
// 2261.376 us; speedup vs baseline: 1.7728x; 1.4315x over previous
//
#include <hip/hip_runtime.h>
#include <cmath>

namespace {

constexpr int Dm  = 512;
constexpr int Bn  = 32;
constexpr int Lq  = 16;
constexpr int V1  = 8193;
constexpr int DFF = 2048;
constexpr int NL  = 2;
constexpr int NT  = 256;

__device__ __forceinline__ float wred(float v) {
#pragma unroll
  for (int off = 32; off; off >>= 1) v += __shfl_down(v, off, 64);
  return v;
}

__device__ __forceinline__ float dot4(const float4 w, const float4 x, float a) {
  a = fmaf(w.x, x.x, a); a = fmaf(w.y, x.y, a);
  a = fmaf(w.z, x.z, a); a = fmaf(w.w, x.w, a);
  return a;
}

__device__ __forceinline__ float pe_val(int pos, int t) {
  const int j2 = (t >> 1) << 1;
  const float div = expf((float)j2 * (-9.210340371976184f / 512.0f));
  const float ang = (float)pos * div;
  return (t & 1) ? cosf(ang) : sinf(ang);
}

// ---- k-chunked batch-amortized GEMM producing partials -------------------
// grid = KS * N/(4*ROWS) blocks. Block: kc = bid % KS, stages x[32][Kc]
// (summing SP source partials, optional relu) XOR-swizzled; each of the 4
// waves computes ROWS rows x 32 batch over the chunk (RH rows per nh-half),
// writes part[kc][32][N]. Bias added at kc==0. Plain loads/stores: coherence
// via kernel boundaries (verified round 4).
template <int KS, int Kc, int SP, bool RELU, int ROWS>
__global__ __launch_bounds__(NT) void fg_part(
    const float* __restrict__ xsrc, int xstride, int pstride,
    const float* __restrict__ W, int K, const float* __restrict__ bias,
    float* __restrict__ part, int N) {
  constexpr int QR = Kc / 4;
  constexpr int RH = ROWS / 2;
  __shared__ float smem[32 * Kc];
  const int bid = (int)blockIdx.x, tid = (int)threadIdx.x;
  const int kc = bid % KS, k0 = kc * Kc;
  for (int idx = tid; idx < 8 * Kc; idx += NT) {
    const int b = idx / QR, q = idx - b * QR;
    const float* s0 = xsrc + (size_t)b * xstride + k0 + (q << 2);
    float4 v = *(const float4*)(s0);
#pragma unroll
    for (int s = 1; s < SP; ++s) {
      const float4 u = *(const float4*)(s0 + (size_t)s * pstride);
      v.x += u.x; v.y += u.y; v.z += u.z; v.w += u.w;
    }
    if (RELU) {
      v.x = fmaxf(v.x, 0.f); v.y = fmaxf(v.y, 0.f);
      v.z = fmaxf(v.z, 0.f); v.w = fmaxf(v.w, 0.f);
    }
    *(float4*)(smem + b * Kc + ((q ^ (b & 7)) << 2)) = v;
  }
  __syncthreads();
  const int lane = tid & 63, wave = tid >> 6;
  const int bl = lane & 31, nh = lane >> 5, sw = bl & 7;
  const float* xb = smem + bl * Kc;
  const int rowjob = (bid / KS) * 4 + wave;
  const int n0 = rowjob * ROWS + nh * RH;
  const float* w = W + (size_t)n0 * K + k0;
  float a[RH];
#pragma unroll
  for (int r = 0; r < RH; ++r) a[r] = 0.f;
#pragma unroll 4
  for (int qq = 0; qq < QR; ++qq) {
    const float4 xv = *(const float4*)(xb + ((qq ^ sw) << 2));
    const float* wq = w + (qq << 2);
#pragma unroll
    for (int r = 0; r < RH; ++r)
      a[r] = dot4(*(const float4*)(wq + (size_t)r * K), xv, a[r]);
  }
  if (kc == 0) {
#pragma unroll
    for (int r = 0; r < RH; ++r) a[r] += bias[n0 + r];
  }
  float* yb = part + (size_t)kc * 32 * N + (size_t)bl * N + n0;
#pragma unroll
  for (int r = 0; r < RH; ++r) yb[r] = a[r];
}

// QKV variant: N=1536, K=512, KS=8, Kc=64, ROWS=4; routes thirds into
// qkvp = [3 segs][8 kc][32][512]. grid 768.
__global__ __launch_bounds__(NT) void fg_qkv_part(const float* __restrict__ x,
    const float* __restrict__ W, const float* __restrict__ bias,
    float* __restrict__ qkvp) {
  constexpr int Kc = 64, QR = 16;
  __shared__ float smem[32 * Kc];
  const int bid = (int)blockIdx.x, tid = (int)threadIdx.x;
  const int kc = bid & 7, k0 = kc << 6;
  for (int idx = tid; idx < 8 * Kc; idx += NT) {
    const int b = idx / QR, q = idx - b * QR;
    const float4 v = *(const float4*)(x + (b << 9) + k0 + (q << 2));
    *(float4*)(smem + b * Kc + ((q ^ (b & 7)) << 2)) = v;
  }
  __syncthreads();
  const int lane = tid & 63, wave = tid >> 6;
  const int bl = lane & 31, nh = lane >> 5, sw = bl & 7;
  const float* xb = smem + bl * Kc;
  const int rowjob = (bid >> 3) * 4 + wave;   // 0..383
  const int n0 = (rowjob << 2) + (nh << 1);   // 0..1535, even
  const float* w = W + (size_t)n0 * Dm + k0;
  float a0 = 0.f, a1 = 0.f;
#pragma unroll 4
  for (int qq = 0; qq < QR; ++qq) {
    const float4 xv = *(const float4*)(xb + ((qq ^ sw) << 2));
    const float* wq = w + (qq << 2);
    a0 = dot4(*(const float4*)(wq), xv, a0);
    a1 = dot4(*(const float4*)(wq + Dm), xv, a1);
  }
  if (kc == 0) { a0 += bias[n0]; a1 += bias[n0 + 1]; }
  const int seg = n0 >> 9;  // 0=q 1=k 2=v
  float* yb = qkvp + (size_t)seg * 131072 + (size_t)kc * 16384 + (bl << 9) + (n0 & 511);
  yb[0] = a0; yb[1] = a1;
}

__device__ __forceinline__ void block_ln(float* s, const float* __restrict__ g,
                                         const float* __restrict__ bb, float* red) {
  const int tid = (int)threadIdx.x;
  float ls = 0.f, lq = 0.f;
  for (int t = tid; t < Dm; t += NT) { const float v = s[t]; ls += v; lq += v * v; }
  ls = wred(ls); lq = wred(lq);
  const int wave = tid >> 6, lane = tid & 63;
  if (lane == 0) { red[wave] = ls; red[4 + wave] = lq; }
  __syncthreads();
  const float sum = red[0] + red[1] + red[2] + red[3];
  const float sq  = red[4] + red[5] + red[6] + red[7];
  const float mean = sum * (1.f / Dm);
  const float var  = sq * (1.f / Dm) - mean * mean;
  const float inv  = 1.f / sqrtf(var + 1e-5f);
  __syncthreads();
  for (int t = tid; t < Dm; t += NT) s[t] = (s[t] - mean) * inv * g[t] + bb[t];
}

// reduce 8 qkv partials, finalize k/v cache slot, scores+softmax+PV
__global__ __launch_bounds__(NT) void attn_core(const float* __restrict__ qkvp,
    float* __restrict__ kcl, float* __restrict__ vcl,
    float* __restrict__ aout, int pos) {
  __shared__ float sQ[Dm], sK[Dm], sV[Dm], sS[Lq];
  const int b = (int)blockIdx.x, tid = (int)threadIdx.x;
  const int lane = tid & 63, wave = tid >> 6;
  const float* qp = qkvp;
  const float* kp = qkvp + 131072;
  const float* vp = qkvp + 262144;
  for (int t = tid; t < Dm; t += NT) {
    const int o = (b << 9) + t;
    float qv = 0.f, kv = 0.f, vv = 0.f;
#pragma unroll
    for (int s = 0; s < 8; ++s) {
      qv += qp[o + s * 16384]; kv += kp[o + s * 16384]; vv += vp[o + s * 16384];
    }
    sQ[t] = qv; sK[t] = kv; sV[t] = vv;
    const int co = ((pos * Bn + b) << 9) + t;
    kcl[co] = kv; vcl[co] = vv;
  }
  __syncthreads();
  for (int j = wave; j <= pos; j += 4) {
    float acc;
    if (j == pos) {
      acc = dot4(*(const float4*)(sK + (lane << 2)),
                 *(const float4*)(sQ + (lane << 2)), 0.f);
      acc = dot4(*(const float4*)(sK + 256 + (lane << 2)),
                 *(const float4*)(sQ + 256 + (lane << 2)), acc);
    } else {
      const float* kr = kcl + ((size_t)(j * Bn + b) << 9);
      acc = dot4(*(const float4*)(kr + (lane << 2)),
                 *(const float4*)(sQ + (lane << 2)), 0.f);
      acc = dot4(*(const float4*)(kr + 256 + (lane << 2)),
                 *(const float4*)(sQ + 256 + (lane << 2)), acc);
    }
    acc = wred(acc);
    if (lane == 0) sS[j] = acc * 0.044194173824159216f;  // 1/sqrt(512)
  }
  __syncthreads();
  if (tid == 0) {
    float m = -1e30f;
    for (int j = 0; j <= pos; ++j) m = fmaxf(m, sS[j]);
    float s = 0.f;
    for (int j = 0; j <= pos; ++j) { const float e = expf(sS[j] - m); sS[j] = e; s += e; }
    const float inv = 1.f / s;
    for (int j = 0; j <= pos; ++j) sS[j] *= inv;
  }
  __syncthreads();
  for (int t = tid; t < Dm; t += NT) {
    float acc = sS[pos] * sV[t];
    for (int j = 0; j < pos; ++j) acc += sS[j] * vcl[((size_t)(j * Bn + b) << 9) + t];
    aout[(b << 9) + t] = acc;
  }
}

// x = LN2(LN1(x + sum of 16 sop parts) + sum of 4 caCp parts)
__global__ __launch_bounds__(NT) void ln12(const float* __restrict__ sop,
    const float* __restrict__ caCp,
    const float* __restrict__ g1, const float* __restrict__ b1,
    const float* __restrict__ g2, const float* __restrict__ b2,
    float* __restrict__ x) {
  __shared__ float sR[Dm], red[8];
  const int b = (int)blockIdx.x, tid = (int)threadIdx.x;
  for (int t = tid; t < Dm; t += NT) {
    const int o = (b << 9) + t;
    float v = x[o];
#pragma unroll
    for (int s = 0; s < 16; ++s) v += sop[o + s * 16384];
    sR[t] = v;
  }
  __syncthreads();
  block_ln(sR, g1, b1, red);
  __syncthreads();
  for (int t = tid; t < Dm; t += NT) {
    const int o = (b << 9) + t;
    float v = sR[t];
#pragma unroll
    for (int s = 0; s < 4; ++s) v += caCp[o + s * 16384];
    sR[t] = v;
  }
  __syncthreads();
  block_ln(sR, g2, b2, red);
  __syncthreads();
  for (int t = tid; t < Dm; t += NT) x[(b << 9) + t] = sR[t];
}

// x = LN3(x + sum of 16 ffn2 parts)  (bias b2 already in part kc==0)
__global__ __launch_bounds__(NT) void ln3red(const float* __restrict__ f2p,
    const float* __restrict__ g3, const float* __restrict__ bb3,
    float* __restrict__ x) {
  __shared__ float sR[Dm], red[8];
  const int b = (int)blockIdx.x, tid = (int)threadIdx.x;
  for (int t = tid; t < Dm; t += NT) {
    const int o = (b << 9) + t;
    float v = x[o];
#pragma unroll
    for (int s = 0; s < 16; ++s) v += f2p[o + s * 16384];
    sR[t] = v;
  }
  __syncthreads();
  block_ln(sR, g3, bb3, red);
  __syncthreads();
  for (int t = tid; t < Dm; t += NT) x[(b << 9) + t] = sR[t];
}

__global__ __launch_bounds__(512) void src_kernel(const int* __restrict__ meanings,
                                                  const float* __restrict__ emb,
                                                  float* __restrict__ src) {
  const int b = (int)blockIdx.x, t = (int)threadIdx.x;
  float s = 0.f;
#pragma unroll
  for (int ty = 0; ty < 8; ++ty) {
    const int idx = meanings[b * 8 + ty] + ty * 32;
    s += emb[(size_t)idx * Dm + t];
  }
  src[b * Dm + t] = s;
}

__global__ __launch_bounds__(512) void embed0(const float* __restrict__ v2e,
                                              float* __restrict__ x) {
  const int b = (int)blockIdx.x, t = (int)threadIdx.x;
  x[(b << 9) + t] = v2e[(size_t)(V1 - 1) * Dm + t] + pe_val(0, t);
}

// logit row 8192 + reduce 2 logits parts -> final rows + argmax + embed
__global__ __launch_bounds__(NT) void argmax_embed(float* __restrict__ x,
    const float* __restrict__ e2v_w, const float* __restrict__ e2v_b,
    const float* __restrict__ v2e, const float* __restrict__ lp,
    float* __restrict__ outLogits, float* __restrict__ outToks, int i) {
  __shared__ float red[8];
  __shared__ float sv[NT];
  __shared__ int   si[NT];
  const int b = (int)blockIdx.x, tid = (int)threadIdx.x;
  const int lane = tid & 63, wave = tid >> 6;
  float ls = 0.f;
  for (int t = tid; t < Dm; t += NT) ls += x[(b << 9) + t] * e2v_w[(size_t)8192 * Dm + t];
  ls = wred(ls);
  if (lane == 0) red[wave] = ls;
  __syncthreads();
  float* row = outLogits + ((size_t)i * Bn + b) * V1;
  if (tid == 0) {
    const float lg = red[0] + red[1] + red[2] + red[3] + e2v_b[8192];
    row[8192] = lg;
    red[4] = lg;
  }
  __syncthreads();
  const float lg = red[4];
  float best = -1e30f; int bi = 0;
  for (int v = tid; v < 8192; v += NT) {
    const float val = lp[(b << 13) + v] + lp[262144 + (b << 13) + v];
    row[v] = val;
    if (val > best) { best = val; bi = v; }  // strided ascending keeps first max
  }
  sv[tid] = best; si[tid] = bi;
  __syncthreads();
  for (int off = 128; off; off >>= 1) {
    if (tid < off) {
      const float v2 = sv[tid + off]; const int i2 = si[tid + off];
      if (v2 > sv[tid] || (v2 == sv[tid] && i2 < si[tid])) { sv[tid] = v2; si[tid] = i2; }
    }
    __syncthreads();
  }
  if (tid == 0) {
    int tok = si[0];
    if (lg > sv[0]) tok = 8192;  // last index wins only on strictly greater
    outToks[i * Bn + b] = (float)tok;
    si[0] = tok;
  }
  __syncthreads();
  const int tok = si[0];
  if (i + 1 < Lq) {
    for (int t = tid; t < Dm; t += NT)
      x[(b << 9) + t] = v2e[(size_t)tok * Dm + t] + pe_val(i + 1, t);
  }
}

}  // namespace

extern "C" void kernel_launch(void* const* d_in, const int* in_sizes, int n_in,
                              void* d_out, int out_size, void* d_ws, size_t ws_size,
                              hipStream_t stream) {
  (void)in_sizes; (void)n_in; (void)out_size; (void)ws_size;
  const int*   meanings  = (const int*)d_in[0];
  const float* emb_table = (const float*)d_in[1];
  const float* v2e_w     = (const float*)d_in[2];
  const float* e2v_w     = (const float*)d_in[3];
  const float* e2v_b     = (const float*)d_in[4];
  const float* sa_qkv_w  = (const float*)d_in[5];
  const float* sa_qkv_b  = (const float*)d_in[6];
  const float* sa_out_w  = (const float*)d_in[7];
  const float* sa_out_b  = (const float*)d_in[8];
  const float* ca_qkv_w  = (const float*)d_in[9];
  const float* ca_qkv_b  = (const float*)d_in[10];
  const float* ca_out_w  = (const float*)d_in[11];
  const float* ca_out_b  = (const float*)d_in[12];
  const float* ffn_w1    = (const float*)d_in[13];
  const float* ffn_b1    = (const float*)d_in[14];
  const float* ffn_w2    = (const float*)d_in[15];
  const float* ffn_b2    = (const float*)d_in[16];
  const float* ln1_g     = (const float*)d_in[17];
  const float* ln1_b     = (const float*)d_in[18];
  const float* ln2_g     = (const float*)d_in[19];
  const float* ln2_b     = (const float*)d_in[20];
  const float* ln3_g     = (const float*)d_in[21];
  const float* ln3_b     = (const float*)d_in[22];

  float* out = (float*)d_out;            // toks [16,32] then logits [16,32,8193]
  float* outLogits = out + Lq * Bn;

  float* f = (float*)d_ws;
  float* src  = f;  f += 16384;          // [32][512]
  float* x    = f;  f += 16384;          // [32][512]
  float* aout = f;  f += 16384;          // [32][512]
  float* caCp = f;  f += 131072;         // [NL][4][32][512]
  float* A    = f;  f += 524288;         // union: qkvp 393216 / sop 262144 /
                                         //        h1p 524288 / lp 524288
  float* f2p  = f;  f += 262144;         // [16][32][512]
  float* kcache = f; f += 524288;        // [NL][16][32][512]
  float* vcache = f;

  src_kernel<<<Bn, 512, 0, stream>>>(meanings, emb_table, src);

  // cross-attn constants (memory len 1): caCp[l] parts of Wo@(Wv src+bv)+bo
  for (int l = 0; l < NL; ++l) {
    fg_part<4, 128, 1, false, 8><<<64, NT, 0, stream>>>(src, Dm, 0,
        ca_qkv_w + ((size_t)l * 3 + 2) * Dm * Dm, Dm,
        ca_qkv_b + l * 3 * Dm + 2 * Dm, A, Dm);
    fg_part<4, 128, 4, false, 8><<<64, NT, 0, stream>>>(A, Dm, 16384,
        ca_out_w + (size_t)l * Dm * Dm, Dm,
        ca_out_b + l * Dm, caCp + (size_t)l * 65536, Dm);
  }

  embed0<<<Bn, 512, 0, stream>>>(v2e_w, x);

  for (int i = 0; i < Lq; ++i) {
    for (int l = 0; l < NL; ++l) {
      float* kcl = kcache + (size_t)l * Lq * Bn * Dm;
      float* vcl = vcache + (size_t)l * Lq * Bn * Dm;
      // qkv partials: [3][8][32][512] into A (768 blocks, 3/CU)
      fg_qkv_part<<<768, NT, 0, stream>>>(x,
          sa_qkv_w + (size_t)l * 3 * Dm * Dm, sa_qkv_b + l * 3 * Dm, A);
      attn_core<<<Bn, NT, 0, stream>>>(A, kcl, vcl, aout, i);
      // sa_out partials: [16][32][512] into A (512 blocks, 2/CU)
      fg_part<16, 32, 1, false, 4><<<512, NT, 0, stream>>>(aout, Dm, 0,
          sa_out_w + (size_t)l * Dm * Dm, Dm, sa_out_b + l * Dm, A, Dm);
      ln12<<<Bn, NT, 0, stream>>>(A, caCp + (size_t)l * 65536,
          ln1_g + l * Dm, ln1_b + l * Dm, ln2_g + l * Dm, ln2_b + l * Dm, x);
      // ffn1 partials: [8][32][2048] into A (1024 blocks, 4/CU)
      fg_part<8, 64, 1, false, 4><<<1024, NT, 0, stream>>>(x, Dm, 0,
          ffn_w1 + (size_t)l * DFF * Dm, Dm, ffn_b1 + l * DFF, A, DFF);
      // ffn2 partials (sums 8 h1 parts + relu): [16][32][512] (512 blocks)
      fg_part<16, 128, 8, true, 4><<<512, NT, 0, stream>>>(A, DFF, 65536,
          ffn_w2 + (size_t)l * Dm * DFF, DFF, ffn_b2 + l * Dm, f2p, Dm);
      ln3red<<<Bn, NT, 0, stream>>>(f2p,
          ln3_g + l * Dm, ln3_b + l * Dm, x);
    }
    // logits partials: [2][32][8192] into A (1024 blocks, 4/CU)
    fg_part<2, 256, 1, false, 4><<<1024, NT, 0, stream>>>(x, Dm, 0,
        e2v_w, Dm, e2v_b, A, 8192);
    argmax_embed<<<Bn, NT, 0, stream>>>(x, e2v_w, e2v_b, v2e_w, A,
        outLogits, out, i);
  }
}